// Round 4
// baseline (548.731 us; speedup 1.0000x reference)
//
#include <hip/hip_runtime.h>
#include <hip/hip_bf16.h>
#include <math.h>

// ---------------------------------------------------------------------------
// GQA attention fwd. bf16 MFMA everywhere, fp32 accum.
// Round 7: attn LDS cut to 64KB (single-buffered V, staged intra-chunk under
// QK^T+softmax via counted vmcnt + raw barriers) -> true 2 blocks/CU with
// slack; setprio around MFMA clusters. 32-cols/wave shared K/V reads kept.
// GEMM: 128xTN counted-vmcnt pipeline (unchanged, proven).
// ---------------------------------------------------------------------------

#define L_SEQ 2048
#define DIM   4096
#define NH    32
#define NKV   8
#define HD    128
#define SCALE 0.08838834764831845f   // 128^-0.5

typedef __bf16 bf16x8 __attribute__((ext_vector_type(8)));
typedef __bf16 bf16x4 __attribute__((ext_vector_type(4)));
typedef __bf16 bf16x2 __attribute__((ext_vector_type(2)));
typedef float  f32x4  __attribute__((ext_vector_type(4)));

// async global->LDS, 16B per lane. LDS dst = uniform base + lane*16.
__device__ __forceinline__ void gld16(const void* g, void* l) {
  __builtin_amdgcn_global_load_lds(
      (const __attribute__((address_space(1))) void*)g,
      (__attribute__((address_space(3))) void*)l, 16, 0, 0);
}

// ---------------- plain cast fp32 -> bf16 ----------------
__global__ void cast_bf16_kernel(const float* __restrict__ in,
                                 __bf16* __restrict__ out, long n4) {
  long i = blockIdx.x * (long)blockDim.x + threadIdx.x;
  if (i >= n4) return;
  float4 f = reinterpret_cast<const float4*>(in)[i];
  bf16x4 o;
  o[0] = (__bf16)f.x; o[1] = (__bf16)f.y; o[2] = (__bf16)f.z; o[3] = (__bf16)f.w;
  reinterpret_cast<bf16x4*>(out)[i] = o;
}

// ---------------- transpose-cast: in[K][N] f32 -> out[N][K] bf16 ----------------
__global__ void tcast_kernel(const float* __restrict__ in0, __bf16* __restrict__ out0,
                             const float* __restrict__ in1, __bf16* __restrict__ out1,
                             int K, int N) {
  __shared__ float tile[32][33];
  const float* in  = blockIdx.z ? in1  : in0;
  __bf16*     out  = blockIdx.z ? out1 : out0;
  int n0 = blockIdx.x * 32, k0 = blockIdx.y * 32;
  int tx = threadIdx.x & 31, ty = threadIdx.x >> 5;   // 256 thr: ty 0..7
#pragma unroll
  for (int i = 0; i < 4; ++i)
    tile[ty + i * 8][tx] = in[(long)(k0 + ty + i * 8) * N + n0 + tx];
  __syncthreads();
#pragma unroll
  for (int i = 0; i < 4; ++i)
    out[(long)(n0 + ty + i * 8) * K + k0 + tx] = (__bf16)tile[tx][ty + i * 8];
}

// ---------------- 128xTN GEMM, C = A[M][K] * Bt[N][K]^T ----------------
// 8 waves (2M x 4N), BK=64, triple-buffered LDS, counted vmcnt pipeline.
// mode 0: fp32 row-major C. mode 2: bf16 head-major C[(col>>7)][row][col&127].
template<int TN>
__global__ __launch_bounds__(512, 2) void gemm_t(
    const __bf16* __restrict__ A, const __bf16* __restrict__ B0,
    const __bf16* __restrict__ B1, void* __restrict__ C0, void* __restrict__ C1,
    int M, int N, int K, int mode) {
  constexpr int ABY = 128 * 64 * 2;       // 16384
  constexpr int BBY = TN * 64 * 2;
  constexpr int BUF = ABY + BBY;
  __shared__ char lds[3 * BUF] __attribute__((aligned(16)));
  const __bf16* Bt = blockIdx.z ? B1 : B0;
  void* C = blockIdx.z ? C1 : C0;

  // T1: bijective XCD swizzle of the (x,y) plane (nwg % 8 == 0 in all uses)
  const int nwg = gridDim.x * gridDim.y;
  const int bid = blockIdx.y * gridDim.x + blockIdx.x;
  const int swz = (bid & 7) * (nwg >> 3) + (bid >> 3);
  const int n0 = (swz % gridDim.x) * TN;
  const int m0 = (swz / gridDim.x) * 128;

  const int t = threadIdx.x, wave = t >> 6, lane = t & 63;
  const int quad = lane >> 4, l16 = lane & 15;
  const int wm = (wave >> 2) * 64, wn = (wave & 3) * (TN / 4);

  // staging source pointers (pre-swizzled global addresses; LDS stays linear)
  const int srow = t >> 3;
  const int scol = ((t & 7) ^ (srow & 7)) * 8;
  const __bf16* pa = A  + (long)(m0 + srow) * K + scol;
  const __bf16* pb = Bt + (long)(n0 + srow) * K + scol;
  const long K64 = (long)64 * K;
  const int ldsA = wave * 1024;           // + lane*16 added by HW
  const int ldsB = ABY + wave * 1024;

  // LDS fragment read offsets (within one buffer)
  int aoff[2][4], boff[2][TN / 64];
#pragma unroll
  for (int ks = 0; ks < 2; ++ks) {
    const int sw = ((ks * 4 + quad) ^ (l16 & 7)) * 16;
#pragma unroll
    for (int i = 0; i < 4; ++i)
      aoff[ks][i] = (wm + i * 16 + l16) * 128 + sw;
#pragma unroll
    for (int i = 0; i < TN / 64; ++i)
      boff[ks][i] = ABY + (wn + i * 16 + l16) * 128 + sw;
  }

  f32x4 acc[4][TN / 64] = {};
  const int nt = K >> 6;

  // prologue: stage tiles 0,1 into buffers 0,1
  {
    char* bb = lds;
#pragma unroll
    for (int pt = 0; pt < 2; ++pt) {
#pragma unroll
      for (int r = 0; r < 2; ++r) gld16(pa + r * K64, bb + ldsA + r * 8192);
#pragma unroll
      for (int r = 0; r < TN / 64; ++r) gld16(pb + r * K64, bb + ldsB + r * 8192);
      pa += 64; pb += 64;
      bb += BUF;
    }
  }

  char* cb = lds;              // compute buffer (tile kt % 3)
  char* sb = lds + 2 * BUF;    // stage buffer   (tile kt+2)

#pragma unroll 1
  for (int kt = 0; kt < nt - 1; ++kt) {
    // tile kt landed (wave-local), tile kt+1 still in flight
    if constexpr (TN == 256) asm volatile("s_waitcnt vmcnt(6)" ::: "memory");
    else                     asm volatile("s_waitcnt vmcnt(4)" ::: "memory");
    __builtin_amdgcn_s_barrier();    // all waves' tile-kt loads landed;
                                     // all waves done reading buffer (kt-1)%3
    bf16x8 af[4], bfr[TN / 64];
#pragma unroll
    for (int i = 0; i < 4; ++i) af[i] = *(const bf16x8*)(cb + aoff[0][i]);
#pragma unroll
    for (int i = 0; i < TN / 64; ++i) bfr[i] = *(const bf16x8*)(cb + boff[0][i]);
    // stage tile kt+2 into the just-freed buffer (overlaps both MFMA phases)
    if (kt + 2 < nt) {
#pragma unroll
      for (int r = 0; r < 2; ++r) gld16(pa + r * K64, sb + ldsA + r * 8192);
#pragma unroll
      for (int r = 0; r < TN / 64; ++r) gld16(pb + r * K64, sb + ldsB + r * 8192);
      pa += 64; pb += 64;
    }
    __builtin_amdgcn_s_setprio(1);
#pragma unroll
    for (int tm = 0; tm < 4; ++tm)
#pragma unroll
      for (int tn = 0; tn < TN / 64; ++tn)
        acc[tm][tn] = __builtin_amdgcn_mfma_f32_16x16x32_bf16(
            af[tm], bfr[tn], acc[tm][tn], 0, 0, 0);
    __builtin_amdgcn_s_setprio(0);
#pragma unroll
    for (int i = 0; i < 4; ++i) af[i] = *(const bf16x8*)(cb + aoff[1][i]);
#pragma unroll
    for (int i = 0; i < TN / 64; ++i) bfr[i] = *(const bf16x8*)(cb + boff[1][i]);
    __builtin_amdgcn_s_setprio(1);
#pragma unroll
    for (int tm = 0; tm < 4; ++tm)
#pragma unroll
      for (int tn = 0; tn < TN / 64; ++tn)
        acc[tm][tn] = __builtin_amdgcn_mfma_f32_16x16x32_bf16(
            af[tm], bfr[tn], acc[tm][tn], 0, 0, 0);
    __builtin_amdgcn_s_setprio(0);
    // rotate buffers
    cb += BUF; if (cb == lds + 3 * BUF) cb = lds;
    sb += BUF; if (sb == lds + 3 * BUF) sb = lds;
  }

  // final tile: drain everything
  asm volatile("s_waitcnt vmcnt(0)" ::: "memory");
  __builtin_amdgcn_s_barrier();
  {
    bf16x8 af[4], bfr[TN / 64];
#pragma unroll
    for (int ks = 0; ks < 2; ++ks) {
#pragma unroll
      for (int i = 0; i < 4; ++i) af[i] = *(const bf16x8*)(cb + aoff[ks][i]);
#pragma unroll
      for (int i = 0; i < TN / 64; ++i) bfr[i] = *(const bf16x8*)(cb + boff[ks][i]);
      __builtin_amdgcn_s_setprio(1);
#pragma unroll
      for (int tm = 0; tm < 4; ++tm)
#pragma unroll
        for (int tn = 0; tn < TN / 64; ++tn)
          acc[tm][tn] = __builtin_amdgcn_mfma_f32_16x16x32_bf16(
              af[tm], bfr[tn], acc[tm][tn], 0, 0, 0);
      __builtin_amdgcn_s_setprio(0);
    }
  }

  // epilogue
#pragma unroll
  for (int tm = 0; tm < 4; ++tm)
#pragma unroll
    for (int tn = 0; tn < TN / 64; ++tn)
#pragma unroll
      for (int r = 0; r < 4; ++r) {
        int row = m0 + wm + tm * 16 + quad * 4 + r;
        int col = n0 + wn + tn * 16 + l16;
        float v = acc[tm][tn][r];
        if (mode == 0) {
          ((float*)C)[(long)row * N + col] = v;
        } else {
          long idx = ((long)(col >> 7) * L_SEQ + row) * HD + (col & 127);
          ((__bf16*)C)[idx] = (__bf16)v;
        }
      }
}

// ---------------- RoPE (traditional / interleaved) ----------------
#define NLOG2_10K 13.287712379549449f   // log2(10000)

__global__ void rope_q_kernel(__bf16* __restrict__ q /*[NH][L][HD]*/) {
  int idx = blockIdx.x * blockDim.x + threadIdx.x;   // (h,l,i) : 32*2048*64
  int i = idx & 63, l = (idx >> 6) & 2047, h = idx >> 17;
  if (h >= NH) return;
  long base = ((long)h * L_SEQ + l) * HD + 2 * i;
  bf16x2 x12 = *(bf16x2*)(q + base);
  float x1 = (float)x12[0], x2 = (float)x12[1];
  float inv = exp2f((float)i * (-NLOG2_10K / 64.0f));
  float s, c; __sincosf((float)l * inv, &s, &c);
  bf16x2 o; o[0] = (__bf16)(x1 * c - x2 * s); o[1] = (__bf16)(x1 * s + x2 * c);
  *(bf16x2*)(q + base) = o;
}

// fused: rope K (in-place bf16 + fp32 GQA-repeated out) + V expand (fp32 out)
__global__ void ropekv_kernel(__bf16* __restrict__ kb /*[NKV][L][HD]*/,
                              const __bf16* __restrict__ vb,
                              float* __restrict__ kout /*[NH][L][HD]*/,
                              float* __restrict__ vout) {
  int idx = blockIdx.x * blockDim.x + threadIdx.x;   // (kv,l,i): 8*2048*64
  int i = idx & 63, l = (idx >> 6) & 2047, kv = idx >> 17;
  if (kv >= NKV) return;
  long base = ((long)kv * L_SEQ + l) * HD + 2 * i;
  bf16x2 x12 = *(bf16x2*)(kb + base);
  float x1 = (float)x12[0], x2 = (float)x12[1];
  float inv = exp2f((float)i * (-NLOG2_10K / 64.0f));
  float s, c; __sincosf((float)l * inv, &s, &c);
  float r1 = x1 * c - x2 * s, r2 = x1 * s + x2 * c;
  bf16x2 o; o[0] = (__bf16)r1; o[1] = (__bf16)r2;
  *(bf16x2*)(kb + base) = o;
  float2 kf; kf.x = r1; kf.y = r2;
  bf16x2 vv = *(const bf16x2*)(vb + base);
  float2 vf; vf.x = (float)vv[0]; vf.y = (float)vv[1];
  long off = (long)(kv * 4) * L_SEQ * HD + (long)l * HD + 2 * i;
#pragma unroll
  for (int rr = 0; rr < 4; ++rr) {
    *(float2*)(kout + off) = kf;
    *(float2*)(vout + off) = vf;
    off += (long)L_SEQ * HD;
  }
}

// ---------------- V transpose: Vh[NKV][L][HD] -> Vt[NKV][HD][L] ----------------
__global__ void vtrans_kernel(const __bf16* __restrict__ Vh, __bf16* __restrict__ Vt) {
  __shared__ __bf16 tile[64 * 65];
  int kv = blockIdx.z, lb = blockIdx.x * 64, db = blockIdx.y * 64;
  int t = threadIdx.x;
#pragma unroll
  for (int it = 0; it < 2; ++it) {
    int c = it * 256 + t, r = c >> 3, pc = c & 7;
    bf16x8 v = *(const bf16x8*)(Vh + ((long)kv * L_SEQ + lb + r) * HD + db + pc * 8);
#pragma unroll
    for (int e = 0; e < 8; ++e) tile[r * 65 + pc * 8 + e] = v[e];
  }
  __syncthreads();
#pragma unroll
  for (int it = 0; it < 2; ++it) {
    int c = it * 256 + t, r = c >> 3, pc = c & 7;
    bf16x8 v;
#pragma unroll
    for (int e = 0; e < 8; ++e) v[e] = tile[(pc * 8 + e) * 65 + r];
    *(bf16x8*)(Vt + ((long)kv * HD + db + r) * L_SEQ + lb + pc * 8) = v;
  }
}

// ---------------- flash attention, S^T formulation, 32 q-cols/wave ----------
// Block = one 128-row q-tile. 4 waves x 32 cols (2 groups of 16); every K/V
// LDS fragment read is shared by both groups' MFMAs. LDS = 64KB (K double-
// buffered, V single-buffered and staged under QK^T+softmax with counted
// vmcnt + raw barriers) -> 2 blocks/CU. Complementary qt pairing.
#define DTHR 8.0f

__global__ __launch_bounds__(256, 2) void attn5_kernel(
    const __bf16* __restrict__ Q, const __bf16* __restrict__ K,
    const __bf16* __restrict__ Vt, __bf16* __restrict__ O /*[L][NH*HD]*/) {
  __shared__ __bf16 Ks[2][64 * 128]  __attribute__((aligned(16)));   // 32KB
  __shared__ __bf16 Vts[128 * 64]    __attribute__((aligned(16)));   // 16KB
  __shared__ __bf16 Ps[128 * 64]     __attribute__((aligned(16)));   // 16KB swz

  const int b = blockIdx.x;                 // 0..511
  const int kvg = b & 7;                    // KV head group -> XCD class
  const int h   = kvg * 4 + ((b >> 3) & 3); // query head
  const int i16 = b >> 5;                   // 0..15
  const int qt  = (i16 < 8) ? (15 - i16) : (i16 - 8);  // complementary pairing
  const int t = threadIdx.x, wave = t >> 6, lane = t & 63;
  const int quad = lane >> 4, l16 = lane & 15;
  const int mw = wave * 32;
  const __bf16* Kh = K  + (long)kvg * L_SEQ * HD;
  const __bf16* Vh = Vt + (long)kvg * HD * L_SEQ;
  const float SL2 = SCALE * 1.44269504f;   // fold log2(e) -> exp2

  // staging maps (XOR swizzle; LDS linear dest, pre-swizzled global src)
  int kr[4], kk[4], vr[4], vk[4];
#pragma unroll
  for (int it = 0; it < 4; ++it) {
    int c = it * 256 + t;
    kr[it] = c >> 4; kk[it] = ((c & 15) ^ (kr[it] & 7)) * 8;
    vr[it] = c >> 3; vk[it] = ((c & 7)  ^ (vr[it] & 7)) * 8;
  }

  const int nchunk = 2 * qt + 2;
  const int jdiag  = 2 * qt;

  int mq[2]; mq[0] = qt * 128 + mw + l16; mq[1] = mq[0] + 16;

  // Q fragments (B operand), both groups
  bf16x8 bq[2][4];
#pragma unroll
  for (int g = 0; g < 2; ++g) {
    const __bf16* qrow = Q + ((long)h * L_SEQ + mq[g]) * HD + quad * 8;
#pragma unroll
    for (int d = 0; d < 4; ++d) bq[g][d] = *(const bf16x8*)(qrow + d * 32);
  }

  f32x4 o_acc[2][8] = {};
  float m_run[2] = {-1e30f, -1e30f}, l_run[2] = {0.f, 0.f};

  // prologue: issue K(0) -> Ks[0]
#pragma unroll
  for (int it = 0; it < 4; ++it)
    gld16(Kh + (long)kr[it] * HD + kk[it],
          (char*)Ks[0] + (size_t)(it * 256 + wave * 64) * 16);

#pragma unroll 1
  for (int j = 0; j < nchunk; ++j) {
    const int kcur = j & 1;
    // K(j) is the only (possibly) outstanding load; ensure it landed, then
    // barrier: all waves see Ks[kcur]; all waves done with Vts (PV j-1).
    asm volatile("s_waitcnt vmcnt(0)" ::: "memory");
    __builtin_amdgcn_s_barrier();

    // stage V(j) (needed only at PV; hides under QK^T+softmax)
#pragma unroll
    for (int it = 0; it < 4; ++it)
      gld16(Vh + (long)vr[it] * L_SEQ + j * 64 + vk[it],
            (char*)Vts + (size_t)(it * 256 + wave * 64) * 16);
    // stage K(j+1)
    if (j + 1 < nchunk) {
#pragma unroll
      for (int it = 0; it < 4; ++it)
        gld16(Kh + (long)((j + 1) * 64 + kr[it]) * HD + kk[it],
              (char*)Ks[kcur ^ 1] + (size_t)(it * 256 + wave * 64) * 16);
    }

    // S^T (64 kv x 32 q-cols per wave): each ak read feeds both groups
    f32x4 s[2][4] = {};
    __builtin_amdgcn_s_setprio(1);
#pragma unroll
    for (int dsi = 0; dsi < 4; ++dsi)
#pragma unroll
      for (int tn = 0; tn < 4; ++tn) {
        bf16x8 ak = *(const bf16x8*)((char*)Ks[kcur] + (tn * 16 + l16) * 256 +
                                     (((dsi * 4 + quad) ^ (l16 & 7)) * 16));
        s[0][tn] = __builtin_amdgcn_mfma_f32_16x16x32_bf16(ak, bq[0][dsi], s[0][tn], 0, 0, 0);
        s[1][tn] = __builtin_amdgcn_mfma_f32_16x16x32_bf16(ak, bq[1][dsi], s[1][tn], 0, 0, 0);
      }
    __builtin_amdgcn_s_setprio(0);

    // per-group: scale + mask + defer-max online softmax + pack P
#pragma unroll
    for (int g = 0; g < 2; ++g) {
#pragma unroll
      for (int tn = 0; tn < 4; ++tn)
#pragma unroll
        for (int r = 0; r < 4; ++r) {
          float v = s[g][tn][r] * SL2;
          if (j >= jdiag && (j * 64 + tn * 16 + quad * 4 + r) > mq[g]) v = -3.0e38f;
          s[g][tn][r] = v;
        }
      float mx = -3.0e38f;
#pragma unroll
      for (int tn = 0; tn < 4; ++tn)
#pragma unroll
        for (int r = 0; r < 4; ++r) mx = fmaxf(mx, s[g][tn][r]);
      mx = fmaxf(mx, __shfl_xor(mx, 16, 64));
      mx = fmaxf(mx, __shfl_xor(mx, 32, 64));

      const bool defer = __all(mx - m_run[g] <= DTHR);
      const float mnew = defer ? m_run[g] : fmaxf(m_run[g], mx);

      float rs = 0.f;
#pragma unroll
      for (int tn = 0; tn < 4; ++tn)
#pragma unroll
        for (int r = 0; r < 4; ++r) {
          float pe = exp2f(s[g][tn][r] - mnew);
          s[g][tn][r] = pe; rs += pe;
        }
      rs += __shfl_xor(rs, 16, 64);
      rs += __shfl_xor(rs, 32, 64);

      if (defer) {
        l_run[g] += rs;
      } else {
        float alpha = exp2f(m_run[g] - mnew);
#pragma unroll
        for (int td = 0; td < 8; ++td)
#pragma unroll
          for (int r = 0; r < 4; ++r) o_acc[g][td][r] *= alpha;
        l_run[g] = l_run[g] * alpha + rs;
        m_run[g] = mnew;
      }

      // P^T -> Ps[col_local][kv], packed 8B stores, XOR swizzle on kv-bytes
      // (wave-private rows: each wave reads back only rows it wrote)
#pragma unroll
      for (int tn = 0; tn < 4; ++tn) {
        bf16x4 pv;
#pragma unroll
        for (int r = 0; r < 4; ++r) pv[r] = (__bf16)s[g][tn][r];
        *(bf16x4*)((char*)Ps + (mw + g * 16 + l16) * 128 +
                   ((tn * 32 + quad * 8) ^ ((l16 & 7) << 4))) = pv;
      }
    }

    // V(j) landed? (older than K(j+1): vmcnt(4) keeps K(j+1) in flight)
    if (j + 1 < nchunk) asm volatile("s_waitcnt vmcnt(4)" ::: "memory");
    else                asm volatile("s_waitcnt vmcnt(0)" ::: "memory");
    __builtin_amdgcn_s_barrier();   // all waves' V(j) in LDS

    // O^T += V^T.P^T : each av read feeds both groups
    __builtin_amdgcn_s_setprio(1);
#pragma unroll
    for (int ks = 0; ks < 2; ++ks) {
      bf16x8 bp0 = *(const bf16x8*)((char*)Ps + (mw + l16) * 128 +
                                    ((ks * 64 + quad * 16) ^ ((l16 & 7) << 4)));
      bf16x8 bp1 = *(const bf16x8*)((char*)Ps + (mw + 16 + l16) * 128 +
                                    ((ks * 64 + quad * 16) ^ ((l16 & 7) << 4)));
#pragma unroll
      for (int td = 0; td < 8; ++td) {
        bf16x8 av = *(const bf16x8*)((char*)Vts + (td * 16 + l16) * 128 +
                                     (((ks * 4 + quad) ^ (l16 & 7)) * 16));
        o_acc[0][td] = __builtin_amdgcn_mfma_f32_16x16x32_bf16(av, bp0, o_acc[0][td], 0, 0, 0);
        o_acc[1][td] = __builtin_amdgcn_mfma_f32_16x16x32_bf16(av, bp1, o_acc[1][td], 0, 0, 0);
      }
    }
    __builtin_amdgcn_s_setprio(0);
  }

  // epilogue: lane column mq[g], d = td*16 + quad*4 + r -> 8B packed stores
#pragma unroll
  for (int g = 0; g < 2; ++g) {
    float inv_l = 1.0f / l_run[g];
#pragma unroll
    for (int td = 0; td < 8; ++td) {
      bf16x4 ov;
#pragma unroll
      for (int r = 0; r < 4; ++r) ov[r] = (__bf16)(o_acc[g][td][r] * inv_l);
      *(bf16x4*)(O + (long)mq[g] * DIM + h * HD + td * 16 + quad * 4) = ov;
    }
  }
}

// ---------------------------------------------------------------------------
extern "C" void kernel_launch(void* const* d_in, const int* in_sizes, int n_in,
                              void* d_out, int out_size, void* d_ws, size_t ws_size,
                              hipStream_t stream) {
  const float* x  = (const float*)d_in[0];
  const float* wq = (const float*)d_in[1];
  const float* wk = (const float*)d_in[2];
  const float* wv = (const float*)d_in[3];
  const float* wo = (const float*)d_in[4];

  float* out   = (float*)d_out;                       // 2048*4096
  float* k_out = out + (long)L_SEQ * DIM;             // [32][2048][128]
  float* v_out = k_out + (long)NH * L_SEQ * HD;

  char* ws = (char*)d_ws;
  __bf16* Xb  = (__bf16*)ws; ws += (long)L_SEQ * DIM * 2;
  __bf16* Wqt = (__bf16*)ws; ws += (long)DIM * DIM * 2;          // [N][K]
  __bf16* Wkt = (__bf16*)ws; ws += (long)DIM * (NKV * HD) * 2;
  __bf16* Wvt = (__bf16*)ws; ws += (long)DIM * (NKV * HD) * 2;
  __bf16* Wot = (__bf16*)ws; ws += (long)DIM * DIM * 2;
  __bf16* Qh  = (__bf16*)ws; ws += (long)NH * L_SEQ * HD * 2;    // [32][2048][128]
  __bf16* Kh  = (__bf16*)ws; ws += (long)NKV * L_SEQ * HD * 2;
  __bf16* Vh  = (__bf16*)ws; ws += (long)NKV * L_SEQ * HD * 2;
  __bf16* Vt  = (__bf16*)ws; ws += (long)NKV * HD * L_SEQ * 2;   // [8][128][2048]
  __bf16* Ob  = (__bf16*)ws; ws += (long)L_SEQ * DIM * 2;

  // weight transpose-casts + x cast
  tcast_kernel<<<dim3(DIM / 32, DIM / 32, 1), 256, 0, stream>>>(wq, Wqt, wq, Wqt, DIM, DIM);
  tcast_kernel<<<dim3((NKV * HD) / 32, DIM / 32, 2), 256, 0, stream>>>(wk, Wkt, wv, Wvt, DIM, NKV * HD);
  tcast_kernel<<<dim3(DIM / 32, DIM / 32, 1), 256, 0, stream>>>(wo, Wot, wo, Wot, DIM, DIM);
  {
    long n = (long)L_SEQ * DIM;
    cast_bf16_kernel<<<dim3(n / 1024), 256, 0, stream>>>(x, Xb, n / 4);
  }
  // projections (pipelined GEMM; KV uses TN=128 -> 256 blocks, full machine)
  gemm_t<256><<<dim3(DIM / 256, L_SEQ / 128, 1), 512, 0, stream>>>(
      Xb, Wqt, Wqt, Qh, Qh, L_SEQ, DIM, DIM, 2);
  gemm_t<128><<<dim3((NKV * HD) / 128, L_SEQ / 128, 2), 512, 0, stream>>>(
      Xb, Wkt, Wvt, Kh, Vh, L_SEQ, NKV * HD, DIM, 2);
  // RoPE + fp32 k/v outputs (GQA-repeated), fused
  rope_q_kernel<<<dim3((NH * L_SEQ * 64) / 256), 256, 0, stream>>>(Qh);
  ropekv_kernel<<<dim3((NKV * L_SEQ * 64) / 256), 256, 0, stream>>>(Kh, Vh, k_out, v_out);
  // V transpose for attention staging
  vtrans_kernel<<<dim3(L_SEQ / 64, HD / 64, NKV), 256, 0, stream>>>(Vh, Vt);
  // flash attention (128-row q-tiles, 32 cols/wave, 2 blocks/CU, 64KB LDS)
  attn5_kernel<<<dim3(512), 256, 0, stream>>>(Qh, Kh, Vt, Ob);
  // output projection
  gemm_t<256><<<dim3(DIM / 256, L_SEQ / 128, 1), 512, 0, stream>>>(
      Ob, Wot, Wot, out, out, L_SEQ, DIM, DIM, 0);
}

// Round 5
// 524.377 us; speedup vs baseline: 1.0464x; 1.0464x over previous
//
#include <hip/hip_runtime.h>
#include <hip/hip_bf16.h>
#include <math.h>

// ---------------------------------------------------------------------------
// GQA attention fwd. bf16 MFMA everywhere, fp32 accum.
// Round 8: attn -> 512-thread / 8-wave blocks (16 q-cols/wave), 128-row
// q-tile, 64KB LDS (K dbuf + single V + swizzled Ps) => long blocks self-
// sustain 2 waves/SIMD and CU-pairs reach 4/SIMD while co-resident.
// GEMM: 128xTN counted-vmcnt pipeline (unchanged, proven).
// ---------------------------------------------------------------------------

#define L_SEQ 2048
#define DIM   4096
#define NH    32
#define NKV   8
#define HD    128
#define SCALE 0.08838834764831845f   // 128^-0.5

typedef __bf16 bf16x8 __attribute__((ext_vector_type(8)));
typedef __bf16 bf16x4 __attribute__((ext_vector_type(4)));
typedef __bf16 bf16x2 __attribute__((ext_vector_type(2)));
typedef float  f32x4  __attribute__((ext_vector_type(4)));

// async global->LDS, 16B per lane. LDS dst = uniform base + lane*16.
__device__ __forceinline__ void gld16(const void* g, void* l) {
  __builtin_amdgcn_global_load_lds(
      (const __attribute__((address_space(1))) void*)g,
      (__attribute__((address_space(3))) void*)l, 16, 0, 0);
}

// ---------------- plain cast fp32 -> bf16 ----------------
__global__ void cast_bf16_kernel(const float* __restrict__ in,
                                 __bf16* __restrict__ out, long n4) {
  long i = blockIdx.x * (long)blockDim.x + threadIdx.x;
  if (i >= n4) return;
  float4 f = reinterpret_cast<const float4*>(in)[i];
  bf16x4 o;
  o[0] = (__bf16)f.x; o[1] = (__bf16)f.y; o[2] = (__bf16)f.z; o[3] = (__bf16)f.w;
  reinterpret_cast<bf16x4*>(out)[i] = o;
}

// ---------------- transpose-cast: in[K][N] f32 -> out[N][K] bf16 ----------------
__global__ void tcast_kernel(const float* __restrict__ in0, __bf16* __restrict__ out0,
                             const float* __restrict__ in1, __bf16* __restrict__ out1,
                             int K, int N) {
  __shared__ float tile[32][33];
  const float* in  = blockIdx.z ? in1  : in0;
  __bf16*     out  = blockIdx.z ? out1 : out0;
  int n0 = blockIdx.x * 32, k0 = blockIdx.y * 32;
  int tx = threadIdx.x & 31, ty = threadIdx.x >> 5;   // 256 thr: ty 0..7
#pragma unroll
  for (int i = 0; i < 4; ++i)
    tile[ty + i * 8][tx] = in[(long)(k0 + ty + i * 8) * N + n0 + tx];
  __syncthreads();
#pragma unroll
  for (int i = 0; i < 4; ++i)
    out[(long)(n0 + ty + i * 8) * K + k0 + tx] = (__bf16)tile[tx][ty + i * 8];
}

// ---------------- 128xTN GEMM, C = A[M][K] * Bt[N][K]^T ----------------
// 8 waves (2M x 4N), BK=64, triple-buffered LDS, counted vmcnt pipeline.
// mode 0: fp32 row-major C. mode 2: bf16 head-major C[(col>>7)][row][col&127].
template<int TN>
__global__ __launch_bounds__(512, 2) void gemm_t(
    const __bf16* __restrict__ A, const __bf16* __restrict__ B0,
    const __bf16* __restrict__ B1, void* __restrict__ C0, void* __restrict__ C1,
    int M, int N, int K, int mode) {
  constexpr int ABY = 128 * 64 * 2;       // 16384
  constexpr int BBY = TN * 64 * 2;
  constexpr int BUF = ABY + BBY;
  __shared__ char lds[3 * BUF] __attribute__((aligned(16)));
  const __bf16* Bt = blockIdx.z ? B1 : B0;
  void* C = blockIdx.z ? C1 : C0;

  // T1: bijective XCD swizzle of the (x,y) plane (nwg % 8 == 0 in all uses)
  const int nwg = gridDim.x * gridDim.y;
  const int bid = blockIdx.y * gridDim.x + blockIdx.x;
  const int swz = (bid & 7) * (nwg >> 3) + (bid >> 3);
  const int n0 = (swz % gridDim.x) * TN;
  const int m0 = (swz / gridDim.x) * 128;

  const int t = threadIdx.x, wave = t >> 6, lane = t & 63;
  const int quad = lane >> 4, l16 = lane & 15;
  const int wm = (wave >> 2) * 64, wn = (wave & 3) * (TN / 4);

  // staging source pointers (pre-swizzled global addresses; LDS stays linear)
  const int srow = t >> 3;
  const int scol = ((t & 7) ^ (srow & 7)) * 8;
  const __bf16* pa = A  + (long)(m0 + srow) * K + scol;
  const __bf16* pb = Bt + (long)(n0 + srow) * K + scol;
  const long K64 = (long)64 * K;
  const int ldsA = wave * 1024;           // + lane*16 added by HW
  const int ldsB = ABY + wave * 1024;

  // LDS fragment read offsets (within one buffer)
  int aoff[2][4], boff[2][TN / 64];
#pragma unroll
  for (int ks = 0; ks < 2; ++ks) {
    const int sw = ((ks * 4 + quad) ^ (l16 & 7)) * 16;
#pragma unroll
    for (int i = 0; i < 4; ++i)
      aoff[ks][i] = (wm + i * 16 + l16) * 128 + sw;
#pragma unroll
    for (int i = 0; i < TN / 64; ++i)
      boff[ks][i] = ABY + (wn + i * 16 + l16) * 128 + sw;
  }

  f32x4 acc[4][TN / 64] = {};
  const int nt = K >> 6;

  // prologue: stage tiles 0,1 into buffers 0,1
  {
    char* bb = lds;
#pragma unroll
    for (int pt = 0; pt < 2; ++pt) {
#pragma unroll
      for (int r = 0; r < 2; ++r) gld16(pa + r * K64, bb + ldsA + r * 8192);
#pragma unroll
      for (int r = 0; r < TN / 64; ++r) gld16(pb + r * K64, bb + ldsB + r * 8192);
      pa += 64; pb += 64;
      bb += BUF;
    }
  }

  char* cb = lds;              // compute buffer (tile kt % 3)
  char* sb = lds + 2 * BUF;    // stage buffer   (tile kt+2)

#pragma unroll 1
  for (int kt = 0; kt < nt - 1; ++kt) {
    // tile kt landed (wave-local), tile kt+1 still in flight
    if constexpr (TN == 256) asm volatile("s_waitcnt vmcnt(6)" ::: "memory");
    else                     asm volatile("s_waitcnt vmcnt(4)" ::: "memory");
    __builtin_amdgcn_s_barrier();    // all waves' tile-kt loads landed;
                                     // all waves done reading buffer (kt-1)%3
    bf16x8 af[4], bfr[TN / 64];
#pragma unroll
    for (int i = 0; i < 4; ++i) af[i] = *(const bf16x8*)(cb + aoff[0][i]);
#pragma unroll
    for (int i = 0; i < TN / 64; ++i) bfr[i] = *(const bf16x8*)(cb + boff[0][i]);
    // stage tile kt+2 into the just-freed buffer (overlaps both MFMA phases)
    if (kt + 2 < nt) {
#pragma unroll
      for (int r = 0; r < 2; ++r) gld16(pa + r * K64, sb + ldsA + r * 8192);
#pragma unroll
      for (int r = 0; r < TN / 64; ++r) gld16(pb + r * K64, sb + ldsB + r * 8192);
      pa += 64; pb += 64;
    }
    __builtin_amdgcn_s_setprio(1);
#pragma unroll
    for (int tm = 0; tm < 4; ++tm)
#pragma unroll
      for (int tn = 0; tn < TN / 64; ++tn)
        acc[tm][tn] = __builtin_amdgcn_mfma_f32_16x16x32_bf16(
            af[tm], bfr[tn], acc[tm][tn], 0, 0, 0);
    __builtin_amdgcn_s_setprio(0);
#pragma unroll
    for (int i = 0; i < 4; ++i) af[i] = *(const bf16x8*)(cb + aoff[1][i]);
#pragma unroll
    for (int i = 0; i < TN / 64; ++i) bfr[i] = *(const bf16x8*)(cb + boff[1][i]);
    __builtin_amdgcn_s_setprio(1);
#pragma unroll
    for (int tm = 0; tm < 4; ++tm)
#pragma unroll
      for (int tn = 0; tn < TN / 64; ++tn)
        acc[tm][tn] = __builtin_amdgcn_mfma_f32_16x16x32_bf16(
            af[tm], bfr[tn], acc[tm][tn], 0, 0, 0);
    __builtin_amdgcn_s_setprio(0);
    // rotate buffers
    cb += BUF; if (cb == lds + 3 * BUF) cb = lds;
    sb += BUF; if (sb == lds + 3 * BUF) sb = lds;
  }

  // final tile: drain everything
  asm volatile("s_waitcnt vmcnt(0)" ::: "memory");
  __builtin_amdgcn_s_barrier();
  {
    bf16x8 af[4], bfr[TN / 64];
#pragma unroll
    for (int ks = 0; ks < 2; ++ks) {
#pragma unroll
      for (int i = 0; i < 4; ++i) af[i] = *(const bf16x8*)(cb + aoff[ks][i]);
#pragma unroll
      for (int i = 0; i < TN / 64; ++i) bfr[i] = *(const bf16x8*)(cb + boff[ks][i]);
      __builtin_amdgcn_s_setprio(1);
#pragma unroll
      for (int tm = 0; tm < 4; ++tm)
#pragma unroll
        for (int tn = 0; tn < TN / 64; ++tn)
          acc[tm][tn] = __builtin_amdgcn_mfma_f32_16x16x32_bf16(
              af[tm], bfr[tn], acc[tm][tn], 0, 0, 0);
      __builtin_amdgcn_s_setprio(0);
    }
  }

  // epilogue
#pragma unroll
  for (int tm = 0; tm < 4; ++tm)
#pragma unroll
    for (int tn = 0; tn < TN / 64; ++tn)
#pragma unroll
      for (int r = 0; r < 4; ++r) {
        int row = m0 + wm + tm * 16 + quad * 4 + r;
        int col = n0 + wn + tn * 16 + l16;
        float v = acc[tm][tn][r];
        if (mode == 0) {
          ((float*)C)[(long)row * N + col] = v;
        } else {
          long idx = ((long)(col >> 7) * L_SEQ + row) * HD + (col & 127);
          ((__bf16*)C)[idx] = (__bf16)v;
        }
      }
}

// ---------------- RoPE (traditional / interleaved) ----------------
#define NLOG2_10K 13.287712379549449f   // log2(10000)

__global__ void rope_q_kernel(__bf16* __restrict__ q /*[NH][L][HD]*/) {
  int idx = blockIdx.x * blockDim.x + threadIdx.x;   // (h,l,i) : 32*2048*64
  int i = idx & 63, l = (idx >> 6) & 2047, h = idx >> 17;
  if (h >= NH) return;
  long base = ((long)h * L_SEQ + l) * HD + 2 * i;
  bf16x2 x12 = *(bf16x2*)(q + base);
  float x1 = (float)x12[0], x2 = (float)x12[1];
  float inv = exp2f((float)i * (-NLOG2_10K / 64.0f));
  float s, c; __sincosf((float)l * inv, &s, &c);
  bf16x2 o; o[0] = (__bf16)(x1 * c - x2 * s); o[1] = (__bf16)(x1 * s + x2 * c);
  *(bf16x2*)(q + base) = o;
}

// fused: rope K (in-place bf16 + fp32 GQA-repeated out) + V expand (fp32 out)
__global__ void ropekv_kernel(__bf16* __restrict__ kb /*[NKV][L][HD]*/,
                              const __bf16* __restrict__ vb,
                              float* __restrict__ kout /*[NH][L][HD]*/,
                              float* __restrict__ vout) {
  int idx = blockIdx.x * blockDim.x + threadIdx.x;   // (kv,l,i): 8*2048*64
  int i = idx & 63, l = (idx >> 6) & 2047, kv = idx >> 17;
  if (kv >= NKV) return;
  long base = ((long)kv * L_SEQ + l) * HD + 2 * i;
  bf16x2 x12 = *(bf16x2*)(kb + base);
  float x1 = (float)x12[0], x2 = (float)x12[1];
  float inv = exp2f((float)i * (-NLOG2_10K / 64.0f));
  float s, c; __sincosf((float)l * inv, &s, &c);
  float r1 = x1 * c - x2 * s, r2 = x1 * s + x2 * c;
  bf16x2 o; o[0] = (__bf16)r1; o[1] = (__bf16)r2;
  *(bf16x2*)(kb + base) = o;
  float2 kf; kf.x = r1; kf.y = r2;
  bf16x2 vv = *(const bf16x2*)(vb + base);
  float2 vf; vf.x = (float)vv[0]; vf.y = (float)vv[1];
  long off = (long)(kv * 4) * L_SEQ * HD + (long)l * HD + 2 * i;
#pragma unroll
  for (int rr = 0; rr < 4; ++rr) {
    *(float2*)(kout + off) = kf;
    *(float2*)(vout + off) = vf;
    off += (long)L_SEQ * HD;
  }
}

// ---------------- V transpose: Vh[NKV][L][HD] -> Vt[NKV][HD][L] ----------------
__global__ void vtrans_kernel(const __bf16* __restrict__ Vh, __bf16* __restrict__ Vt) {
  __shared__ __bf16 tile[64 * 65];
  int kv = blockIdx.z, lb = blockIdx.x * 64, db = blockIdx.y * 64;
  int t = threadIdx.x;
#pragma unroll
  for (int it = 0; it < 2; ++it) {
    int c = it * 256 + t, r = c >> 3, pc = c & 7;
    bf16x8 v = *(const bf16x8*)(Vh + ((long)kv * L_SEQ + lb + r) * HD + db + pc * 8);
#pragma unroll
    for (int e = 0; e < 8; ++e) tile[r * 65 + pc * 8 + e] = v[e];
  }
  __syncthreads();
#pragma unroll
  for (int it = 0; it < 2; ++it) {
    int c = it * 256 + t, r = c >> 3, pc = c & 7;
    bf16x8 v;
#pragma unroll
    for (int e = 0; e < 8; ++e) v[e] = tile[(pc * 8 + e) * 65 + r];
    *(bf16x8*)(Vt + ((long)kv * HD + db + r) * L_SEQ + lb + pc * 8) = v;
  }
}

// ---------------- flash attention, S^T formulation, 8 waves/block ----------
// Block = one 128-row q-tile, 512 threads (8 waves x 16 q-cols). LDS 64KB:
// K double-buffered, V single-buffered (staged under QK^T+softmax, counted
// vmcnt + raw barriers), Ps XOR-swizzled. 2 blocks/CU co-resident; the long
// block alone sustains 2 waves/SIMD. Complementary dispatch pairing.
#define DTHR 8.0f

__global__ __launch_bounds__(512, 4) void attn6_kernel(
    const __bf16* __restrict__ Q, const __bf16* __restrict__ K,
    const __bf16* __restrict__ Vt, __bf16* __restrict__ O /*[L][NH*HD]*/) {
  __shared__ __bf16 Ks[2][64 * 128]  __attribute__((aligned(16)));   // 32KB
  __shared__ __bf16 Vts[128 * 64]    __attribute__((aligned(16)));   // 16KB
  __shared__ __bf16 Ps[128 * 64]     __attribute__((aligned(16)));   // 16KB swz

  const int b = blockIdx.x;                 // 0..511
  const int kvg = b & 7;                    // KV head group -> XCD class
  const int h   = kvg * 4 + ((b >> 3) & 3); // query head
  const int i16 = b >> 5;                   // 0..15
  const int qt  = (i16 < 8) ? (15 - i16) : (i16 - 8);  // complementary pairing
  const int t = threadIdx.x, wave = t >> 6, lane = t & 63;
  const int quad = lane >> 4, l16 = lane & 15;
  const int mw = wave * 16;
  const __bf16* Kh = K  + (long)kvg * L_SEQ * HD;
  const __bf16* Vh = Vt + (long)kvg * HD * L_SEQ;
  const float SL2 = SCALE * 1.44269504f;   // fold log2(e) -> exp2

  // staging maps (XOR swizzle; LDS linear dest, pre-swizzled global src)
  // 512 threads -> 2 gld16 each per 16KB tile
  int kr[2], kk[2], vr[2], vk[2];
#pragma unroll
  for (int it = 0; it < 2; ++it) {
    int c = it * 512 + t;
    kr[it] = c >> 4; kk[it] = ((c & 15) ^ (kr[it] & 7)) * 8;
    vr[it] = c >> 3; vk[it] = ((c & 7)  ^ (vr[it] & 7)) * 8;
  }

  const int nchunk = 2 * qt + 2;
  const int jdiag  = 2 * qt;

  const int mq = qt * 128 + mw + l16;       // this lane's q column

  // Q fragments (B operand)
  bf16x8 bq[4];
  {
    const __bf16* qrow = Q + ((long)h * L_SEQ + mq) * HD + quad * 8;
#pragma unroll
    for (int d = 0; d < 4; ++d) bq[d] = *(const bf16x8*)(qrow + d * 32);
  }

  f32x4 o_acc[8] = {};
  float m_run = -1e30f, l_run = 0.f;

  // prologue: issue K(0) -> Ks[0]
#pragma unroll
  for (int it = 0; it < 2; ++it)
    gld16(Kh + (long)kr[it] * HD + kk[it],
          (char*)Ks[0] + (size_t)(it * 512 + wave * 64) * 16);

#pragma unroll 1
  for (int j = 0; j < nchunk; ++j) {
    const int kcur = j & 1;
    // K(j) is the only (possibly) outstanding load; ensure it landed, then
    // barrier: all waves see Ks[kcur]; all waves done with Vts (PV j-1).
    asm volatile("s_waitcnt vmcnt(0)" ::: "memory");
    __builtin_amdgcn_s_barrier();

    // stage V(j) (needed only at PV; hides under QK^T+softmax)
#pragma unroll
    for (int it = 0; it < 2; ++it)
      gld16(Vh + (long)vr[it] * L_SEQ + j * 64 + vk[it],
            (char*)Vts + (size_t)(it * 512 + wave * 64) * 16);
    // stage K(j+1)
    if (j + 1 < nchunk) {
#pragma unroll
      for (int it = 0; it < 2; ++it)
        gld16(Kh + (long)((j + 1) * 64 + kr[it]) * HD + kk[it],
              (char*)Ks[kcur ^ 1] + (size_t)(it * 512 + wave * 64) * 16);
    }

    // S^T (64 kv x 16 q-cols per wave): 16 MFMA
    f32x4 s[4] = {};
    __builtin_amdgcn_s_setprio(1);
#pragma unroll
    for (int dsi = 0; dsi < 4; ++dsi)
#pragma unroll
      for (int tn = 0; tn < 4; ++tn) {
        bf16x8 ak = *(const bf16x8*)((char*)Ks[kcur] + (tn * 16 + l16) * 256 +
                                     (((dsi * 4 + quad) ^ (l16 & 7)) * 16));
        s[tn] = __builtin_amdgcn_mfma_f32_16x16x32_bf16(ak, bq[dsi], s[tn], 0, 0, 0);
      }
    __builtin_amdgcn_s_setprio(0);

    // scale + mask + defer-max online softmax
#pragma unroll
    for (int tn = 0; tn < 4; ++tn)
#pragma unroll
      for (int r = 0; r < 4; ++r) {
        float v = s[tn][r] * SL2;
        if (j >= jdiag && (j * 64 + tn * 16 + quad * 4 + r) > mq) v = -3.0e38f;
        s[tn][r] = v;
      }
    float mx = -3.0e38f;
#pragma unroll
    for (int tn = 0; tn < 4; ++tn)
#pragma unroll
      for (int r = 0; r < 4; ++r) mx = fmaxf(mx, s[tn][r]);
    mx = fmaxf(mx, __shfl_xor(mx, 16, 64));
    mx = fmaxf(mx, __shfl_xor(mx, 32, 64));

    const bool defer = __all(mx - m_run <= DTHR);
    const float mnew = defer ? m_run : fmaxf(m_run, mx);

    float rs = 0.f;
#pragma unroll
    for (int tn = 0; tn < 4; ++tn)
#pragma unroll
      for (int r = 0; r < 4; ++r) {
        float pe = exp2f(s[tn][r] - mnew);
        s[tn][r] = pe; rs += pe;
      }
    rs += __shfl_xor(rs, 16, 64);
    rs += __shfl_xor(rs, 32, 64);

    if (defer) {
      l_run += rs;
    } else {
      float alpha = exp2f(m_run - mnew);
#pragma unroll
      for (int td = 0; td < 8; ++td)
#pragma unroll
        for (int r = 0; r < 4; ++r) o_acc[td][r] *= alpha;
      l_run = l_run * alpha + rs;
      m_run = mnew;
    }

    // P^T -> Ps[col_local][kv], packed 8B stores, XOR swizzle on kv-bytes
    // (wave-private rows: each wave reads back only rows it wrote)
#pragma unroll
    for (int tn = 0; tn < 4; ++tn) {
      bf16x4 pv;
#pragma unroll
      for (int r = 0; r < 4; ++r) pv[r] = (__bf16)s[tn][r];
      *(bf16x4*)((char*)Ps + (mw + l16) * 128 +
                 ((tn * 32 + quad * 8) ^ ((l16 & 7) << 4))) = pv;
    }

    // V(j) landed? (older than K(j+1): vmcnt(2) keeps K(j+1) in flight)
    if (j + 1 < nchunk) asm volatile("s_waitcnt vmcnt(2)" ::: "memory");
    else                asm volatile("s_waitcnt vmcnt(0)" ::: "memory");
    __builtin_amdgcn_s_barrier();   // all waves' V(j) in LDS

    // O^T += V^T.P^T : 16 MFMA
    __builtin_amdgcn_s_setprio(1);
#pragma unroll
    for (int ks = 0; ks < 2; ++ks) {
      bf16x8 bp = *(const bf16x8*)((char*)Ps + (mw + l16) * 128 +
                                   ((ks * 64 + quad * 16) ^ ((l16 & 7) << 4)));
#pragma unroll
      for (int td = 0; td < 8; ++td) {
        bf16x8 av = *(const bf16x8*)((char*)Vts + (td * 16 + l16) * 128 +
                                     (((ks * 4 + quad) ^ (l16 & 7)) * 16));
        o_acc[td] = __builtin_amdgcn_mfma_f32_16x16x32_bf16(av, bp, o_acc[td], 0, 0, 0);
      }
    }
    __builtin_amdgcn_s_setprio(0);
  }

  // epilogue: lane column mq, d = td*16 + quad*4 + r -> 8B packed stores
  float inv_l = 1.0f / l_run;
#pragma unroll
  for (int td = 0; td < 8; ++td) {
    bf16x4 ov;
#pragma unroll
    for (int r = 0; r < 4; ++r) ov[r] = (__bf16)(o_acc[td][r] * inv_l);
    *(bf16x4*)(O + (long)mq * DIM + h * HD + td * 16 + quad * 4) = ov;
  }
}

// ---------------------------------------------------------------------------
extern "C" void kernel_launch(void* const* d_in, const int* in_sizes, int n_in,
                              void* d_out, int out_size, void* d_ws, size_t ws_size,
                              hipStream_t stream) {
  const float* x  = (const float*)d_in[0];
  const float* wq = (const float*)d_in[1];
  const float* wk = (const float*)d_in[2];
  const float* wv = (const float*)d_in[3];
  const float* wo = (const float*)d_in[4];

  float* out   = (float*)d_out;                       // 2048*4096
  float* k_out = out + (long)L_SEQ * DIM;             // [32][2048][128]
  float* v_out = k_out + (long)NH * L_SEQ * HD;

  char* ws = (char*)d_ws;
  __bf16* Xb  = (__bf16*)ws; ws += (long)L_SEQ * DIM * 2;
  __bf16* Wqt = (__bf16*)ws; ws += (long)DIM * DIM * 2;          // [N][K]
  __bf16* Wkt = (__bf16*)ws; ws += (long)DIM * (NKV * HD) * 2;
  __bf16* Wvt = (__bf16*)ws; ws += (long)DIM * (NKV * HD) * 2;
  __bf16* Wot = (__bf16*)ws; ws += (long)DIM * DIM * 2;
  __bf16* Qh  = (__bf16*)ws; ws += (long)NH * L_SEQ * HD * 2;    // [32][2048][128]
  __bf16* Kh  = (__bf16*)ws; ws += (long)NKV * L_SEQ * HD * 2;
  __bf16* Vh  = (__bf16*)ws; ws += (long)NKV * L_SEQ * HD * 2;
  __bf16* Vt  = (__bf16*)ws; ws += (long)NKV * HD * L_SEQ * 2;   // [8][128][2048]
  __bf16* Ob  = (__bf16*)ws; ws += (long)L_SEQ * DIM * 2;

  // weight transpose-casts + x cast
  tcast_kernel<<<dim3(DIM / 32, DIM / 32, 1), 256, 0, stream>>>(wq, Wqt, wq, Wqt, DIM, DIM);
  tcast_kernel<<<dim3((NKV * HD) / 32, DIM / 32, 2), 256, 0, stream>>>(wk, Wkt, wv, Wvt, DIM, NKV * HD);
  tcast_kernel<<<dim3(DIM / 32, DIM / 32, 1), 256, 0, stream>>>(wo, Wot, wo, Wot, DIM, DIM);
  {
    long n = (long)L_SEQ * DIM;
    cast_bf16_kernel<<<dim3(n / 1024), 256, 0, stream>>>(x, Xb, n / 4);
  }
  // projections (pipelined GEMM; KV uses TN=128 -> 256 blocks, full machine)
  gemm_t<256><<<dim3(DIM / 256, L_SEQ / 128, 1), 512, 0, stream>>>(
      Xb, Wqt, Wqt, Qh, Qh, L_SEQ, DIM, DIM, 2);
  gemm_t<128><<<dim3((NKV * HD) / 128, L_SEQ / 128, 2), 512, 0, stream>>>(
      Xb, Wkt, Wvt, Kh, Vh, L_SEQ, NKV * HD, DIM, 2);
  // RoPE + fp32 k/v outputs (GQA-repeated), fused
  rope_q_kernel<<<dim3((NH * L_SEQ * 64) / 256), 256, 0, stream>>>(Qh);
  ropekv_kernel<<<dim3((NKV * L_SEQ * 64) / 256), 256, 0, stream>>>(Kh, Vh, k_out, v_out);
  // V transpose for attention staging
  vtrans_kernel<<<dim3(L_SEQ / 64, HD / 64, NKV), 256, 0, stream>>>(Vh, Vt);
  // flash attention (128-row q-tiles, 8 waves/block, 2 blocks/CU, 64KB LDS)
  attn6_kernel<<<dim3(512), 512, 0, stream>>>(Qh, Kh, Vt, Ob);
  // output projection
  gemm_t<256><<<dim3(DIM / 256, L_SEQ / 128, 1), 512, 0, stream>>>(
      Ob, Wot, Wot, out, out, L_SEQ, DIM, DIM, 0);
}